// Round 4
// baseline (5915.503 us; speedup 1.0000x reference)
//
#include <hip/hip_runtime.h>
#include <cstdint>
#include <cstddef>

// Problem constants
#define kSEQ 100
#define kB   200
#define kNP  512
#define kNG  4096
#define kMP  256     // padded M for recurrent/encoder GEMMs
#define KSPLIT 8

typedef __bf16 bf16_t;
typedef bf16_t bf16x8 __attribute__((ext_vector_type(8)));
typedef float  f32x4  __attribute__((ext_vector_type(4)));

__device__ __forceinline__ unsigned short f2bf(float f) {
    unsigned int u = __builtin_bit_cast(unsigned int, f);
    unsigned int r = (u + 0x7FFFu + ((u >> 16) & 1u)) >> 16;
    return (unsigned short)r;
}
__device__ __forceinline__ float bf2f(unsigned short b) {
    unsigned int u = ((unsigned int)b) << 16;
    return __builtin_bit_cast(float, u);
}

// ---------------------------------------------------------------------------
// Split fp32 -> (hi, lo) bf16 pair.  n4 = number of float4 groups.
// ---------------------------------------------------------------------------
__global__ __launch_bounds__(256)
void k_split(const float* __restrict__ src, unsigned short* __restrict__ hi,
             unsigned short* __restrict__ lo, int n4) {
    int i = blockIdx.x * 256 + threadIdx.x;
    if (i >= n4) return;
    float4 v = ((const float4*)src)[i];
    ushort4 h, l;
    h.x = f2bf(v.x); l.x = f2bf(v.x - bf2f(h.x));
    h.y = f2bf(v.y); l.y = f2bf(v.y - bf2f(h.y));
    h.z = f2bf(v.z); l.z = f2bf(v.z - bf2f(h.z));
    h.w = f2bf(v.w); l.w = f2bf(v.w - bf2f(h.w));
    ((ushort4*)hi)[i] = h;
    ((ushort4*)lo)[i] = l;
}

// ---------------------------------------------------------------------------
// Split-precision bf16 MFMA GEMM:  part[ks][m][n] = sum_k A[m][k]*B[n][k].
// A = (Ahi+Alo), B = (Bhi+Blo); 3 MFMA products.
// A-fragments are loaded DIRECTLY from global (A is L2-resident: 4 MB read
// 32x/step) -> LDS only stages B, halving LDS traffic (the prior bottleneck:
// 192 KB/block/iter LDS vs 466 cyc MFMA).  Grid: (N/128, kMP/128, KSPLIT).
// ---------------------------------------------------------------------------
__global__ __launch_bounds__(256)
void k_gemm_split(const unsigned short* __restrict__ Ahi, const unsigned short* __restrict__ Alo, int lda,
                  const unsigned short* __restrict__ Bhi, const unsigned short* __restrict__ Blo, int ldb,
                  float* __restrict__ part, int kPerChunk) {
    __shared__ __align__(16) unsigned short sBh[128 * 64];
    __shared__ __align__(16) unsigned short sBl[128 * 64];

    const int tid  = threadIdx.x;
    const int lane = tid & 63;
    const int wid  = tid >> 6;
    const int wr   = wid >> 1;   // wave row (0..1)
    const int wc   = wid & 1;    // wave col (0..1)
    const int m0   = blockIdx.y * 128;
    const int n0   = blockIdx.x * 128;
    const int kBase = blockIdx.z * kPerChunk;

    f32x4 acc[4][4];
#pragma unroll
    for (int i = 0; i < 4; i++)
#pragma unroll
        for (int j = 0; j < 4; j++) acc[i][j] = (f32x4){0.f, 0.f, 0.f, 0.f};

    // A-fragment per-lane base offsets (loop-invariant): row*lda + k-subgroup
    const int fr = lane & 15;            // row within 16x16 fragment
    const int kg = (lane >> 4) * 8;      // k-elem offset within 32-deep block
    size_t aoff[4];
#pragma unroll
    for (int fm = 0; fm < 4; fm++)
        aoff[fm] = (size_t)(m0 + wr * 64 + fm * 16 + fr) * (size_t)lda + kg;

    const int sr = tid >> 1;          // staging row 0..127
    const int sc = (tid & 1) * 32;    // staging col offset (bf16 elems)
    const unsigned int swzrow = ((unsigned)sr & 7u) << 4;
    const unsigned int sbase  = (unsigned)sr * 128u + (unsigned)(tid & 1) * 64u;

    for (int kb = 0; kb < kPerChunk; kb += 64) {
        const int k0 = kBase + kb;

        // ---- A fragments straight from global (L2-hot), both ks2 halves ----
        bf16x8 ah[2][4], al[2][4];
#pragma unroll
        for (int ks2 = 0; ks2 < 2; ks2++)
#pragma unroll
            for (int fm = 0; fm < 4; fm++) {
                ah[ks2][fm] = *(const bf16x8*)(Ahi + aoff[fm] + k0 + ks2 * 32);
                al[ks2][fm] = *(const bf16x8*)(Alo + aoff[fm] + k0 + ks2 * 32);
            }

        __syncthreads();   // prev iter's LDS reads done before restage
        {
            const uint4* gBh = (const uint4*)(Bhi + (size_t)(n0 + sr) * (size_t)ldb + k0 + sc);
            const uint4* gBl = (const uint4*)(Blo + (size_t)(n0 + sr) * (size_t)ldb + k0 + sc);
#pragma unroll
            for (int i = 0; i < 4; i++) {
                unsigned int off = (sbase + (unsigned)i * 16u) ^ swzrow;
                *(uint4*)((char*)sBh + off) = gBh[i];
                *(uint4*)((char*)sBl + off) = gBl[i];
            }
        }
        __syncthreads();

#pragma unroll
        for (int ks2 = 0; ks2 < 2; ks2++) {
            bf16x8 bh[4], bl[4];
            const unsigned int klane = (unsigned)(lane >> 4) * 16u + (unsigned)ks2 * 64u;
#pragma unroll
            for (int fn = 0; fn < 4; fn++) {
                const unsigned int row = (unsigned)(wc * 64 + fn * 16 + (lane & 15));
                const unsigned int off = (row * 128u + klane) ^ ((row & 7u) << 4);
                bh[fn] = *(const bf16x8*)((const char*)sBh + off);
                bl[fn] = *(const bf16x8*)((const char*)sBl + off);
            }
#pragma unroll
            for (int fm = 0; fm < 4; fm++)
#pragma unroll
                for (int fn = 0; fn < 4; fn++) {
                    acc[fm][fn] = __builtin_amdgcn_mfma_f32_16x16x32_bf16(ah[ks2][fm], bh[fn], acc[fm][fn], 0, 0, 0);
                    acc[fm][fn] = __builtin_amdgcn_mfma_f32_16x16x32_bf16(ah[ks2][fm], bl[fn], acc[fm][fn], 0, 0, 0);
                    acc[fm][fn] = __builtin_amdgcn_mfma_f32_16x16x32_bf16(al[ks2][fm], bh[fn], acc[fm][fn], 0, 0, 0);
                }
        }
    }

    float* po = part + (size_t)blockIdx.z * ((size_t)kMP * kNG);
#pragma unroll
    for (int fm = 0; fm < 4; fm++)
#pragma unroll
        for (int fn = 0; fn < 4; fn++) {
            const int row0 = m0 + wr * 64 + fm * 16 + ((lane >> 4) << 2);
            const int col  = n0 + wc * 64 + fn * 16 + (lane & 15);
#pragma unroll
            for (int j = 0; j < 4; j++)
                po[(size_t)(row0 + j) * kNG + col] = acc[fm][fn][j];
        }
}

// ---------------------------------------------------------------------------
// Reduce KSPLIT K-partials; mode 1: add velocity*W_ih^T, ReLU, store g (fp32
// + bf16 copy) and next-h (bf16 hi/lo).  mode 0 (encoder): just split h0.
// Grid: (4, kB), 256 threads, 4 g's per thread.
// ---------------------------------------------------------------------------
__global__ __launch_bounds__(256)
void k_reduce(const float* __restrict__ part,
              const float* __restrict__ velocity, const float* __restrict__ W_ih,
              float* __restrict__ gout, unsigned short* __restrict__ gb,
              unsigned short* __restrict__ hhi, unsigned short* __restrict__ hlo,
              int t, int mode) {
    const int b = blockIdx.y;
    const int g = blockIdx.x * 1024 + threadIdx.x * 4;

    float4 s = *(const float4*)(part + (size_t)b * kNG + g);
    float v0 = s.x, v1 = s.y, v2 = s.z, v3 = s.w;
#pragma unroll
    for (int ks = 1; ks < KSPLIT; ks++) {
        float4 p = *(const float4*)(part + (size_t)ks * ((size_t)kMP * kNG) + (size_t)b * kNG + g);
        v0 += p.x; v1 += p.y; v2 += p.z; v3 += p.w;
    }
    if (mode == 1) {
        const float2 vel = *(const float2*)(velocity + ((size_t)t * kB + b) * 2);
        const float4 w01 = *(const float4*)(W_ih + (size_t)g * 2);
        const float4 w23 = *(const float4*)(W_ih + (size_t)g * 2 + 4);
        v0 = fmaxf(0.f, v0 + vel.x * w01.x + vel.y * w01.y);
        v1 = fmaxf(0.f, v1 + vel.x * w01.z + vel.y * w01.w);
        v2 = fmaxf(0.f, v2 + vel.x * w23.x + vel.y * w23.y);
        v3 = fmaxf(0.f, v3 + vel.x * w23.z + vel.y * w23.w);
        float4 o; o.x = v0; o.y = v1; o.z = v2; o.w = v3;
        *(float4*)(gout + ((size_t)t * kB + b) * kNG + g) = o;
    }
    ushort4 hh, hl;
    hh.x = f2bf(v0); hl.x = f2bf(v0 - bf2f(hh.x));
    hh.y = f2bf(v1); hl.y = f2bf(v1 - bf2f(hh.y));
    hh.z = f2bf(v2); hl.z = f2bf(v2 - bf2f(hh.z));
    hh.w = f2bf(v3); hl.w = f2bf(v3 - bf2f(hh.w));
    *(ushort4*)(hhi + (size_t)b * kNG + g) = hh;
    *(ushort4*)(hlo + (size_t)b * kNG + g) = hl;
    if (mode == 1 && gb)
        *(ushort4*)(gb + ((size_t)t * kB + b) * kNG + g) = hh;
}

// ---------------------------------------------------------------------------
// Decoder: logits[r][p] = sum_g G[r][g] * Wdec[p][g], single-bf16 MFMA.
// Gb (bf16 G) used if non-null, else Gf (fp32) converted during staging.
// Flat grid 632, XCD-colocated decode: the 4 n-tiles of an m-panel land on
// the same XCD so G rows are fetched into that L2 once (not 4x from HBM).
// ---------------------------------------------------------------------------
__global__ __launch_bounds__(256)
void k_dec(const float* __restrict__ Gf, const unsigned short* __restrict__ Gb,
           const unsigned short* __restrict__ Bhi, float* __restrict__ out) {
    __shared__ __align__(16) unsigned short sA[128 * 64];
    __shared__ __align__(16) unsigned short sB[128 * 64];

    const int bid  = blockIdx.x;        // 0..631
    const int xcd  = bid & 7;
    const int idx  = bid >> 3;          // 0..78
    const int tile = xcd * 79 + idx;    // tile = m_t*4 + n_t
    if (tile >= 157 * 4) return;        // uniform early-out (before any barrier)
    const int m0 = (tile >> 2) * 128;
    const int n0 = (tile & 3) * 128;

    const int tid  = threadIdx.x;
    const int lane = tid & 63;
    const int wid  = tid >> 6;
    const int wr   = wid >> 1;
    const int wc   = wid & 1;
    const int M    = kSEQ * kB;   // 20000

    f32x4 acc[4][4];
#pragma unroll
    for (int i = 0; i < 4; i++)
#pragma unroll
        for (int j = 0; j < 4; j++) acc[i][j] = (f32x4){0.f, 0.f, 0.f, 0.f};

    const int sr   = tid >> 1;
    const int half = tid & 1;
    const int sc   = half * 32;                    // bf16-elem col offset
    const unsigned int swzrow = ((unsigned)sr & 7u) << 4;
    const unsigned int sbase  = (unsigned)sr * 128u + (unsigned)half * 64u;
    int arow = m0 + sr; if (arow > M - 1) arow = M - 1;

    for (int k0 = 0; k0 < kNG; k0 += 64) {
        __syncthreads();
        if (Gb) {
            // bf16 G: identical pattern to B-staging (measured 0 conflicts)
            const uint4* gA = (const uint4*)(Gb + (size_t)arow * kNG + k0 + sc);
#pragma unroll
            for (int i = 0; i < 4; i++) {
                unsigned int off = (sbase + (unsigned)i * 16u) ^ swzrow;
                *(uint4*)((char*)sA + off) = gA[i];
            }
        } else {
            // fp32 fallback: convert + packed b128 stores (same addresses)
            const float4* gA = (const float4*)(Gf + (size_t)arow * kNG + k0 + sc);
#pragma unroll
            for (int i = 0; i < 4; i++) {
                float4 a0 = gA[2 * i], a1 = gA[2 * i + 1];
                uint4 u;
                u.x = (unsigned)f2bf(a0.x) | ((unsigned)f2bf(a0.y) << 16);
                u.y = (unsigned)f2bf(a0.z) | ((unsigned)f2bf(a0.w) << 16);
                u.z = (unsigned)f2bf(a1.x) | ((unsigned)f2bf(a1.y) << 16);
                u.w = (unsigned)f2bf(a1.z) | ((unsigned)f2bf(a1.w) << 16);
                unsigned int off = (sbase + (unsigned)i * 16u) ^ swzrow;
                *(uint4*)((char*)sA + off) = u;
            }
        }
        {
            const uint4* gB = (const uint4*)(Bhi + (size_t)(n0 + sr) * kNG + k0 + sc);
#pragma unroll
            for (int i = 0; i < 4; i++) {
                unsigned int off = (sbase + (unsigned)i * 16u) ^ swzrow;
                *(uint4*)((char*)sB + off) = gB[i];
            }
        }
        __syncthreads();
#pragma unroll
        for (int ks2 = 0; ks2 < 2; ks2++) {
            bf16x8 a[4], bfr[4];
            const unsigned int klane = (unsigned)(lane >> 4) * 16u + (unsigned)ks2 * 64u;
#pragma unroll
            for (int fm = 0; fm < 4; fm++) {
                const unsigned int row = (unsigned)(wr * 64 + fm * 16 + (lane & 15));
                const unsigned int off = (row * 128u + klane) ^ ((row & 7u) << 4);
                a[fm] = *(const bf16x8*)((const char*)sA + off);
            }
#pragma unroll
            for (int fn = 0; fn < 4; fn++) {
                const unsigned int row = (unsigned)(wc * 64 + fn * 16 + (lane & 15));
                const unsigned int off = (row * 128u + klane) ^ ((row & 7u) << 4);
                bfr[fn] = *(const bf16x8*)((const char*)sB + off);
            }
#pragma unroll
            for (int fm = 0; fm < 4; fm++)
#pragma unroll
                for (int fn = 0; fn < 4; fn++)
                    acc[fm][fn] = __builtin_amdgcn_mfma_f32_16x16x32_bf16(a[fm], bfr[fn], acc[fm][fn], 0, 0, 0);
        }
    }

#pragma unroll
    for (int fm = 0; fm < 4; fm++)
#pragma unroll
        for (int fn = 0; fn < 4; fn++) {
            const int row0 = m0 + wr * 64 + fm * 16 + ((lane >> 4) << 2);
            const int col  = n0 + wc * 64 + fn * 16 + (lane & 15);
#pragma unroll
            for (int j = 0; j < 4; j++) {
                const int row = row0 + j;
                if (row < M) out[(size_t)row * kNP + col] = acc[fm][fn][j];
            }
        }
}

// ---------------------------------------------------------------------------
extern "C" void kernel_launch(void* const* d_in, const int* in_sizes, int n_in,
                              void* d_out, int out_size, void* d_ws, size_t ws_size,
                              hipStream_t stream) {
    const float* velocity = (const float*)d_in[0];
    const float* init_pc  = (const float*)d_in[1];
    const float* W_enc    = (const float*)d_in[2];
    const float* W_ih     = (const float*)d_in[3];
    const float* W_hh     = (const float*)d_in[4];
    const float* W_dec    = (const float*)d_in[5];

    float* logits = (float*)d_out;                         // (100,200,512)
    float* gout   = logits + (size_t)kSEQ * kB * kNP;      // (100,200,4096)

    char* ws = (char*)d_ws;
    size_t off = 0;
    auto alloc = [&](size_t bytes) -> void* {
        void* p = ws + off;
        off += (bytes + 255) & ~(size_t)255;
        return p;
    };
    unsigned short* whh_hi  = (unsigned short*)alloc((size_t)kNG * kNG * 2);
    unsigned short* whh_lo  = (unsigned short*)alloc((size_t)kNG * kNG * 2);
    unsigned short* wdec_hi = (unsigned short*)alloc((size_t)kNP * kNG * 2);
    unsigned short* wdec_lo = (unsigned short*)alloc((size_t)kNP * kNG * 2);
    unsigned short* wenc_hi = (unsigned short*)alloc((size_t)kNG * kNP * 2);
    unsigned short* wenc_lo = (unsigned short*)alloc((size_t)kNG * kNP * 2);
    unsigned short* ip_hi   = (unsigned short*)alloc((size_t)kMP * kNP * 2);
    unsigned short* ip_lo   = (unsigned short*)alloc((size_t)kMP * kNP * 2);
    unsigned short* h_hi[2], *h_lo[2];
    h_hi[0] = (unsigned short*)alloc((size_t)kMP * kNG * 2);
    h_lo[0] = (unsigned short*)alloc((size_t)kMP * kNG * 2);
    h_hi[1] = (unsigned short*)alloc((size_t)kMP * kNG * 2);
    h_lo[1] = (unsigned short*)alloc((size_t)kMP * kNG * 2);
    float* partial = (float*)alloc((size_t)KSPLIT * kMP * kNG * 4);
    // optional bf16 copy of g for the decoder (164 MB) — only if ws allows
    unsigned short* gb = nullptr;
    if (ws_size >= off + (size_t)kSEQ * kB * kNG * 2 + 4096)
        gb = (unsigned short*)alloc((size_t)kSEQ * kB * kNG * 2);

    // zero the init_pc pad rows (h pads feed discarded partial rows only)
    hipMemsetAsync(ip_hi + (size_t)kB * kNP, 0, (size_t)(kMP - kB) * kNP * 2, stream);
    hipMemsetAsync(ip_lo + (size_t)kB * kNP, 0, (size_t)(kMP - kB) * kNP * 2, stream);

    // --- pre-split weights / initial state ---
    int n4;
    n4 = kNG * kNG / 4;
    k_split<<<(n4 + 255) / 256, 256, 0, stream>>>(W_hh, whh_hi, whh_lo, n4);
    n4 = kNP * kNG / 4;
    k_split<<<(n4 + 255) / 256, 256, 0, stream>>>(W_dec, wdec_hi, wdec_lo, n4);
    n4 = kNG * kNP / 4;
    k_split<<<(n4 + 255) / 256, 256, 0, stream>>>(W_enc, wenc_hi, wenc_lo, n4);
    n4 = kB * kNP / 4;
    k_split<<<(n4 + 255) / 256, 256, 0, stream>>>(init_pc, ip_hi, ip_lo, n4);

    dim3 gG(kNG / 128, kMP / 128, KSPLIT);   // (32, 2, 8) = 512 blocks
    dim3 gR(4, kB);

    // --- encoder: h0 = init_pc @ W_enc^T ---
    k_gemm_split<<<gG, 256, 0, stream>>>(ip_hi, ip_lo, kNP, wenc_hi, wenc_lo, kNP, partial, kNP / KSPLIT);
    k_reduce<<<gR, 256, 0, stream>>>(partial, velocity, W_ih, nullptr, nullptr, h_hi[0], h_lo[0], 0, 0);

    // --- recurrent scan ---
    int p = 0;
    for (int t = 0; t < kSEQ; t++) {
        k_gemm_split<<<gG, 256, 0, stream>>>(h_hi[p], h_lo[p], kNG, whh_hi, whh_lo, kNG, partial, kNG / KSPLIT);
        k_reduce<<<gR, 256, 0, stream>>>(partial, velocity, W_ih, gout, gb, h_hi[p ^ 1], h_lo[p ^ 1], t, 1);
        p ^= 1;
    }

    // --- decoder ---
    k_dec<<<632, 256, 0, stream>>>(gout, gb, wdec_hi, logits);
}

// Round 5
// 2733.022 us; speedup vs baseline: 2.1645x; 2.1645x over previous
//
#include <hip/hip_runtime.h>
#include <cstdint>
#include <cstddef>

// Problem constants
#define kSEQ 100
#define kB   200
#define kNP  512
#define kNG  4096
#define kMP  256     // padded M for recurrent/encoder GEMMs
#define KSPLIT 8

typedef _Float16 f16_t;
typedef f16_t f16x8 __attribute__((ext_vector_type(8)));
typedef f16_t f16x4 __attribute__((ext_vector_type(4)));
typedef float f32x4 __attribute__((ext_vector_type(4)));

// ---------------------------------------------------------------------------
// Convert fp32 -> fp16 (RTN).  n8 = number of 8-float groups.
// ---------------------------------------------------------------------------
__global__ __launch_bounds__(256)
void k_half(const float* __restrict__ src, f16_t* __restrict__ dst, int n8) {
    int i = blockIdx.x * 256 + threadIdx.x;
    if (i >= n8) return;
    const float4* s = (const float4*)src + (size_t)i * 2;
    float4 v0 = s[0], v1 = s[1];
    f16x8 h;
    h[0] = (f16_t)v0.x; h[1] = (f16_t)v0.y; h[2] = (f16_t)v0.z; h[3] = (f16_t)v0.w;
    h[4] = (f16_t)v1.x; h[5] = (f16_t)v1.y; h[6] = (f16_t)v1.z; h[7] = (f16_t)v1.w;
    *(f16x8*)(dst + (size_t)i * 8) = h;
}

// ---------------------------------------------------------------------------
// Single-product fp16 MFMA GEMM:  part[ks][m][n] = sum_k A[m][k]*B[n][k]
// over this block's K-chunk.  Round-3 proven structure (LDS staging with
// XOR swizzle, 128x128 tile, 4 waves of 64x64), fp16 instead of bf16 3-prod:
// 3x fewer MFMA, 2x less LDS traffic, 2x less W bytes.
// Grid: (N/128, kMP/128, KSPLIT) = 512 blocks -> 2 blocks/CU.
// ---------------------------------------------------------------------------
__global__ __launch_bounds__(256)
void k_gemm_f16(const f16_t* __restrict__ A, int lda,
                const f16_t* __restrict__ B, int ldb,
                float* __restrict__ part, int kPerChunk) {
    __shared__ __align__(16) f16_t sA[128 * 64];
    __shared__ __align__(16) f16_t sB[128 * 64];

    const int tid  = threadIdx.x;
    const int lane = tid & 63;
    const int wid  = tid >> 6;
    const int wr   = wid >> 1;   // wave row (0..1)
    const int wc   = wid & 1;    // wave col (0..1)
    const int m0   = blockIdx.y * 128;
    const int n0   = blockIdx.x * 128;
    const int kBase = blockIdx.z * kPerChunk;

    f32x4 acc[4][4];
#pragma unroll
    for (int i = 0; i < 4; i++)
#pragma unroll
        for (int j = 0; j < 4; j++) acc[i][j] = (f32x4){0.f, 0.f, 0.f, 0.f};

    const int sr = tid >> 1;          // staging row 0..127
    const int sc = (tid & 1) * 32;    // staging col offset (f16 elems)
    const unsigned int swzrow = ((unsigned)sr & 7u) << 4;
    const unsigned int sbase  = (unsigned)sr * 128u + (unsigned)(tid & 1) * 64u;

    for (int kb = 0; kb < kPerChunk; kb += 64) {
        const int k0 = kBase + kb;
        __syncthreads();
        {
            const uint4* gA = (const uint4*)(A + (size_t)(m0 + sr) * (size_t)lda + k0 + sc);
            const uint4* gB = (const uint4*)(B + (size_t)(n0 + sr) * (size_t)ldb + k0 + sc);
#pragma unroll
            for (int i = 0; i < 4; i++) {
                unsigned int off = (sbase + (unsigned)i * 16u) ^ swzrow;
                *(uint4*)((char*)sA + off) = gA[i];
                *(uint4*)((char*)sB + off) = gB[i];
            }
        }
        __syncthreads();
#pragma unroll
        for (int ks2 = 0; ks2 < 2; ks2++) {
            f16x8 a[4], b[4];
            const unsigned int klane = (unsigned)(lane >> 4) * 16u + (unsigned)ks2 * 64u;
#pragma unroll
            for (int fm = 0; fm < 4; fm++) {
                const unsigned int row = (unsigned)(wr * 64 + fm * 16 + (lane & 15));
                const unsigned int off = (row * 128u + klane) ^ ((row & 7u) << 4);
                a[fm] = *(const f16x8*)((const char*)sA + off);
            }
#pragma unroll
            for (int fn = 0; fn < 4; fn++) {
                const unsigned int row = (unsigned)(wc * 64 + fn * 16 + (lane & 15));
                const unsigned int off = (row * 128u + klane) ^ ((row & 7u) << 4);
                b[fn] = *(const f16x8*)((const char*)sB + off);
            }
#pragma unroll
            for (int fm = 0; fm < 4; fm++)
#pragma unroll
                for (int fn = 0; fn < 4; fn++)
                    acc[fm][fn] = __builtin_amdgcn_mfma_f32_16x16x32_f16(a[fm], b[fn], acc[fm][fn], 0, 0, 0);
        }
    }

    float* po = part + (size_t)blockIdx.z * ((size_t)kMP * kNG);
#pragma unroll
    for (int fm = 0; fm < 4; fm++)
#pragma unroll
        for (int fn = 0; fn < 4; fn++) {
            const int row0 = m0 + wr * 64 + fm * 16 + ((lane >> 4) << 2);
            const int col  = n0 + wc * 64 + fn * 16 + (lane & 15);
#pragma unroll
            for (int j = 0; j < 4; j++)
                po[(size_t)(row0 + j) * kNG + col] = acc[fm][fn][j];
        }
}

// ---------------------------------------------------------------------------
// Reduce KSPLIT K-partials; mode 1: add velocity*W_ih^T, ReLU, store g (fp32
// + fp16 copy for decoder) and next-h (fp16).  mode 0 (encoder): just h0.
// Grid: (4, kB), 256 threads, 4 g's per thread.
// ---------------------------------------------------------------------------
__global__ __launch_bounds__(256)
void k_reduce(const float* __restrict__ part,
              const float* __restrict__ velocity, const float* __restrict__ W_ih,
              float* __restrict__ gout, f16_t* __restrict__ gb,
              f16_t* __restrict__ hout, int t, int mode) {
    const int b = blockIdx.y;
    const int g = blockIdx.x * 1024 + threadIdx.x * 4;

    float4 s = *(const float4*)(part + (size_t)b * kNG + g);
    float v0 = s.x, v1 = s.y, v2 = s.z, v3 = s.w;
#pragma unroll
    for (int ks = 1; ks < KSPLIT; ks++) {
        float4 p = *(const float4*)(part + (size_t)ks * ((size_t)kMP * kNG) + (size_t)b * kNG + g);
        v0 += p.x; v1 += p.y; v2 += p.z; v3 += p.w;
    }
    if (mode == 1) {
        const float2 vel = *(const float2*)(velocity + ((size_t)t * kB + b) * 2);
        const float4 w01 = *(const float4*)(W_ih + (size_t)g * 2);
        const float4 w23 = *(const float4*)(W_ih + (size_t)g * 2 + 4);
        v0 = fmaxf(0.f, v0 + vel.x * w01.x + vel.y * w01.y);
        v1 = fmaxf(0.f, v1 + vel.x * w01.z + vel.y * w01.w);
        v2 = fmaxf(0.f, v2 + vel.x * w23.x + vel.y * w23.y);
        v3 = fmaxf(0.f, v3 + vel.x * w23.z + vel.y * w23.w);
        float4 o; o.x = v0; o.y = v1; o.z = v2; o.w = v3;
        *(float4*)(gout + ((size_t)t * kB + b) * kNG + g) = o;
    }
    f16x4 h;
    h[0] = (f16_t)v0; h[1] = (f16_t)v1; h[2] = (f16_t)v2; h[3] = (f16_t)v3;
    *(f16x4*)(hout + (size_t)b * kNG + g) = h;
    if (mode == 1 && gb)
        *(f16x4*)(gb + ((size_t)t * kB + b) * kNG + g) = h;
}

// ---------------------------------------------------------------------------
// Decoder: logits[r][p] = sum_g G[r][g] * Wdec[p][g], single fp16 MFMA.
// Gb (fp16 G) used if non-null, else Gf (fp32) converted during staging.
// Flat grid 632, XCD-colocated decode: the 4 n-tiles of an m-panel land on
// the same XCD so G rows are fetched into that L2 once.
// ---------------------------------------------------------------------------
__global__ __launch_bounds__(256)
void k_dec(const float* __restrict__ Gf, const f16_t* __restrict__ Gb,
           const f16_t* __restrict__ Wd, float* __restrict__ out) {
    __shared__ __align__(16) f16_t sA[128 * 64];
    __shared__ __align__(16) f16_t sB[128 * 64];

    const int bid  = blockIdx.x;        // 0..631
    const int xcd  = bid & 7;
    const int idx  = bid >> 3;          // 0..78
    const int tile = xcd * 79 + idx;    // tile = m_t*4 + n_t
    if (tile >= 157 * 4) return;        // uniform early-out (before any barrier)
    const int m0 = (tile >> 2) * 128;
    const int n0 = (tile & 3) * 128;

    const int tid  = threadIdx.x;
    const int lane = tid & 63;
    const int wid  = tid >> 6;
    const int wr   = wid >> 1;
    const int wc   = wid & 1;
    const int M    = kSEQ * kB;   // 20000

    f32x4 acc[4][4];
#pragma unroll
    for (int i = 0; i < 4; i++)
#pragma unroll
        for (int j = 0; j < 4; j++) acc[i][j] = (f32x4){0.f, 0.f, 0.f, 0.f};

    const int sr   = tid >> 1;
    const int half = tid & 1;
    const int sc   = half * 32;                    // f16-elem col offset
    const unsigned int swzrow = ((unsigned)sr & 7u) << 4;
    const unsigned int sbase  = (unsigned)sr * 128u + (unsigned)half * 64u;
    int arow = m0 + sr; if (arow > M - 1) arow = M - 1;

    for (int k0 = 0; k0 < kNG; k0 += 64) {
        __syncthreads();
        if (Gb) {
            const uint4* gA = (const uint4*)(Gb + (size_t)arow * kNG + k0 + sc);
#pragma unroll
            for (int i = 0; i < 4; i++) {
                unsigned int off = (sbase + (unsigned)i * 16u) ^ swzrow;
                *(uint4*)((char*)sA + off) = gA[i];
            }
        } else {
            const float4* gA = (const float4*)(Gf + (size_t)arow * kNG + k0 + sc);
#pragma unroll
            for (int i = 0; i < 4; i++) {
                float4 a0 = gA[2 * i], a1 = gA[2 * i + 1];
                f16x8 u;
                u[0] = (f16_t)a0.x; u[1] = (f16_t)a0.y; u[2] = (f16_t)a0.z; u[3] = (f16_t)a0.w;
                u[4] = (f16_t)a1.x; u[5] = (f16_t)a1.y; u[6] = (f16_t)a1.z; u[7] = (f16_t)a1.w;
                unsigned int off = (sbase + (unsigned)i * 16u) ^ swzrow;
                *(f16x8*)((char*)sA + off) = u;
            }
        }
        {
            const uint4* gB = (const uint4*)(Wd + (size_t)(n0 + sr) * kNG + k0 + sc);
#pragma unroll
            for (int i = 0; i < 4; i++) {
                unsigned int off = (sbase + (unsigned)i * 16u) ^ swzrow;
                *(uint4*)((char*)sB + off) = gB[i];
            }
        }
        __syncthreads();
#pragma unroll
        for (int ks2 = 0; ks2 < 2; ks2++) {
            f16x8 a[4], b[4];
            const unsigned int klane = (unsigned)(lane >> 4) * 16u + (unsigned)ks2 * 64u;
#pragma unroll
            for (int fm = 0; fm < 4; fm++) {
                const unsigned int row = (unsigned)(wr * 64 + fm * 16 + (lane & 15));
                const unsigned int off = (row * 128u + klane) ^ ((row & 7u) << 4);
                a[fm] = *(const f16x8*)((const char*)sA + off);
            }
#pragma unroll
            for (int fn = 0; fn < 4; fn++) {
                const unsigned int row = (unsigned)(wc * 64 + fn * 16 + (lane & 15));
                const unsigned int off = (row * 128u + klane) ^ ((row & 7u) << 4);
                b[fn] = *(const f16x8*)((const char*)sB + off);
            }
#pragma unroll
            for (int fm = 0; fm < 4; fm++)
#pragma unroll
                for (int fn = 0; fn < 4; fn++)
                    acc[fm][fn] = __builtin_amdgcn_mfma_f32_16x16x32_f16(a[fm], b[fn], acc[fm][fn], 0, 0, 0);
        }
    }

#pragma unroll
    for (int fm = 0; fm < 4; fm++)
#pragma unroll
        for (int fn = 0; fn < 4; fn++) {
            const int row0 = m0 + wr * 64 + fm * 16 + ((lane >> 4) << 2);
            const int col  = n0 + wc * 64 + fn * 16 + (lane & 15);
#pragma unroll
            for (int j = 0; j < 4; j++) {
                const int row = row0 + j;
                if (row < M) out[(size_t)row * kNP + col] = acc[fm][fn][j];
            }
        }
}

// ---------------------------------------------------------------------------
extern "C" void kernel_launch(void* const* d_in, const int* in_sizes, int n_in,
                              void* d_out, int out_size, void* d_ws, size_t ws_size,
                              hipStream_t stream) {
    const float* velocity = (const float*)d_in[0];
    const float* init_pc  = (const float*)d_in[1];
    const float* W_enc    = (const float*)d_in[2];
    const float* W_ih     = (const float*)d_in[3];
    const float* W_hh     = (const float*)d_in[4];
    const float* W_dec    = (const float*)d_in[5];

    float* logits = (float*)d_out;                         // (100,200,512)
    float* gout   = logits + (size_t)kSEQ * kB * kNP;      // (100,200,4096)

    char* ws = (char*)d_ws;
    size_t off = 0;
    auto alloc = [&](size_t bytes) -> void* {
        void* p = ws + off;
        off += (bytes + 255) & ~(size_t)255;
        return p;
    };
    f16_t* whh  = (f16_t*)alloc((size_t)kNG * kNG * 2);
    f16_t* wdec = (f16_t*)alloc((size_t)kNP * kNG * 2);
    f16_t* wenc = (f16_t*)alloc((size_t)kNG * kNP * 2);
    f16_t* ip   = (f16_t*)alloc((size_t)kMP * kNP * 2);
    f16_t* h_buf[2];
    h_buf[0] = (f16_t*)alloc((size_t)kMP * kNG * 2);
    h_buf[1] = (f16_t*)alloc((size_t)kMP * kNG * 2);
    float* partial = (float*)alloc((size_t)KSPLIT * kMP * kNG * 4);
    // fp16 copy of g for the decoder (164 MB) — only if ws allows
    f16_t* gb = nullptr;
    if (ws_size >= off + (size_t)kSEQ * kB * kNG * 2 + 4096)
        gb = (f16_t*)alloc((size_t)kSEQ * kB * kNG * 2);

    // zero the init_pc pad rows (h pads feed discarded partial rows only)
    hipMemsetAsync(ip + (size_t)kB * kNP, 0, (size_t)(kMP - kB) * kNP * 2, stream);

    // --- fp32 -> fp16 conversions ---
    int n8;
    n8 = kNG * kNG / 8;
    k_half<<<(n8 + 255) / 256, 256, 0, stream>>>(W_hh, whh, n8);
    n8 = kNP * kNG / 8;
    k_half<<<(n8 + 255) / 256, 256, 0, stream>>>(W_dec, wdec, n8);
    n8 = kNG * kNP / 8;
    k_half<<<(n8 + 255) / 256, 256, 0, stream>>>(W_enc, wenc, n8);
    n8 = kB * kNP / 8;
    k_half<<<(n8 + 255) / 256, 256, 0, stream>>>(init_pc, ip, n8);

    dim3 gG(kNG / 128, kMP / 128, KSPLIT);   // (32, 2, 8) = 512 blocks
    dim3 gR(4, kB);

    // --- encoder: h0 = init_pc @ W_enc^T ---
    k_gemm_f16<<<gG, 256, 0, stream>>>(ip, kNP, wenc, kNP, partial, kNP / KSPLIT);
    k_reduce<<<gR, 256, 0, stream>>>(partial, velocity, W_ih, nullptr, nullptr, h_buf[0], 0, 0);

    // --- recurrent scan ---
    int p = 0;
    for (int t = 0; t < kSEQ; t++) {
        k_gemm_f16<<<gG, 256, 0, stream>>>(h_buf[p], kNG, whh, kNG, partial, kNG / KSPLIT);
        k_reduce<<<gR, 256, 0, stream>>>(partial, velocity, W_ih, gout, gb, h_buf[p ^ 1], t, 1);
        p ^= 1;
    }

    // --- decoder ---
    k_dec<<<632, 256, 0, stream>>>(gout, gb, wdec, logits);
}